// Round 4
// baseline (273.527 us; speedup 1.0000x reference)
//
#include <hip/hip_runtime.h>
#include <hip/hip_cooperative_groups.h>
#include <math.h>

namespace cg = cooperative_groups;

#define N_   64
#define C_   256
#define S_   16
#define HW_  3136      // 56*56
#define HW4_ 784       // HW/4
#define ROWS_   (N_ * C_)       // 16384 (n,c) rows
#define BLOCKS_ 1024
#define RPB_    (ROWS_ / BLOCKS_) // 16 rows per block
#define RPW_    (RPB_ / 4)        // 4 rows per wave (4 waves/block)

typedef float f32x4 __attribute__((ext_vector_type(4)));

__device__ __forceinline__ float sigmoidf_(float v) {
    return 1.0f / (1.0f + expf(-v));
}

// One persistent cooperative kernel. 1024 blocks x 256 threads, co-resident
// at 4 blocks/CU (launch_bounds caps VGPR to 128).
//   Phase A: pool — each block reduces a contiguous 16-row slab (wave-per-row).
//   Phase B: MLP  — blocks 0..63 each compute g[n,:] for one image.
//   Phase C: scale — same slab, x re-read hits Infinity Cache, nt-stores for out
//            so the write stream doesn't evict x mid-phase.
__global__ __launch_bounds__(256, 4) void se_fused(
    const float* __restrict__ x,
    const float* __restrict__ w1, const float* __restrict__ b1,
    const float* __restrict__ w2, const float* __restrict__ b2,
    float* __restrict__ out, float* __restrict__ s, float* __restrict__ g)
{
    cg::grid_group grid = cg::this_grid();
    const int t    = threadIdx.x;
    const int wave = t >> 6;
    const int lane = t & 63;
    const int base = blockIdx.x * RPB_;

    __shared__ float s_sh[C_];
    __shared__ float h_sh[S_];

    // ---- Phase A: global average pool, wave-per-row ----
    #pragma unroll
    for (int rr = 0; rr < RPW_; ++rr) {
        const int row = base + wave * RPW_ + rr;
        const f32x4* xr = reinterpret_cast<const f32x4*>(x + (size_t)row * HW_);
        float sum = 0.f;
        for (int i = lane; i < HW4_; i += 64) {
            f32x4 v = xr[i];
            sum += (v.x + v.y) + (v.z + v.w);
        }
        #pragma unroll
        for (int off = 32; off; off >>= 1) sum += __shfl_down(sum, off, 64);
        if (lane == 0) s[row] = sum * (1.0f / (float)HW_);
    }
    grid.sync();

    // ---- Phase B: tiny MLP, one block per image for blocks 0..63 ----
    if (blockIdx.x < N_) {
        const int n = blockIdx.x;
        s_sh[t] = s[n * C_ + t];
        __syncthreads();
        const int j  = t >> 4;     // 0..15 hidden unit
        const int sl = t & 15;     // 0..15 sub-lane
        float p = 0.f;
        #pragma unroll
        for (int k = sl; k < C_; k += 16) p += s_sh[k] * w1[j * C_ + k];
        #pragma unroll
        for (int m = 8; m; m >>= 1) p += __shfl_xor(p, m, 64);
        if (sl == 0) {
            float hv = p + b1[j];
            h_sh[j] = hv * sigmoidf_(hv);   // swish
        }
        __syncthreads();
        float acc = b2[t];
        #pragma unroll
        for (int k = 0; k < S_; ++k) acc += h_sh[k] * w2[t * S_ + k];
        g[n * C_ + t] = sigmoidf_(acc);
    }
    grid.sync();

    // ---- Phase C: out = x * g, same slab, nt stores ----
    #pragma unroll
    for (int rr = 0; rr < RPW_; ++rr) {
        const int row = base + wave * RPW_ + rr;
        const float gv = g[row];
        const f32x4* xr = reinterpret_cast<const f32x4*>(x + (size_t)row * HW_);
        f32x4* orow = reinterpret_cast<f32x4*>(out + (size_t)row * HW_);
        for (int i = lane; i < HW4_; i += 64) {
            f32x4 v = xr[i];
            v *= gv;
            __builtin_nontemporal_store(v, &orow[i]);
        }
    }
}

extern "C" void kernel_launch(void* const* d_in, const int* in_sizes, int n_in,
                              void* d_out, int out_size, void* d_ws, size_t ws_size,
                              hipStream_t stream) {
    const float* x  = (const float*)d_in[0];
    const float* w1 = (const float*)d_in[1];
    const float* b1 = (const float*)d_in[2];
    const float* w2 = (const float*)d_in[3];
    const float* b2 = (const float*)d_in[4];
    float* out = (float*)d_out;

    float* s = (float*)d_ws;          // N*C floats
    float* g = s + N_ * C_;           // N*C floats

    void* args[] = { (void*)&x, (void*)&w1, (void*)&b1, (void*)&w2, (void*)&b2,
                     (void*)&out, (void*)&s, (void*)&g };
    hipLaunchCooperativeKernel((const void*)se_fused, dim3(BLOCKS_), dim3(256),
                               args, 0, stream);
}

// Round 5
// 230.444 us; speedup vs baseline: 1.1870x; 1.1870x over previous
//
#include <hip/hip_runtime.h>
#include <math.h>

#define N_   64
#define C_   256
#define S_   16
#define HW_  3136      // 56*56
#define HW4_ 784       // HW/4
#define ROWS_ (N_ * C_)        // 16384 (n,c) rows
#define PBLOCKS_ 4096          // pool blocks: 4 rows each (wave-per-row)

typedef float f32x4 __attribute__((ext_vector_type(4)));

__device__ __forceinline__ float sigmoidf_(float v) {
    return 1.0f / (1.0f + expf(-v));
}

// Kernel 1: pool (wave-per-row, deep unrolled loads) + last-block-per-image MLP.
// 4096 blocks x 256 threads; block b covers rows [4b, 4b+3] (one row per wave),
// all 64 blocks of image n = b>>6. The last block to finish image n runs the
// tiny MLP for that image (counter in ws, zeroed by memset each call).
__global__ __launch_bounds__(256) void se_pool_mlp(
    const float* __restrict__ x,
    const float* __restrict__ w1, const float* __restrict__ b1,
    const float* __restrict__ w2, const float* __restrict__ b2,
    float* __restrict__ s, float* __restrict__ g, unsigned* __restrict__ cnt)
{
    const int t    = threadIdx.x;
    const int wave = t >> 6;
    const int lane = t & 63;
    const int row  = blockIdx.x * 4 + wave;   // one row per wave
    const int n    = blockIdx.x >> 6;         // 64 blocks per image

    const f32x4* xr = reinterpret_cast<const f32x4*>(x + (size_t)row * HW_);

    // 784 = 12*64 + 16: 12 unrolled independent loads + predicated tail.
    f32x4 acc = {0.f, 0.f, 0.f, 0.f};
    #pragma unroll
    for (int u = 0; u < 12; ++u) {
        f32x4 v = xr[lane + 64 * u];
        acc += v;
    }
    float sum = (acc.x + acc.y) + (acc.z + acc.w);
    if (lane < 16) {
        f32x4 v = xr[lane + 768];
        sum += (v.x + v.y) + (v.z + v.w);
    }
    #pragma unroll
    for (int off = 32; off; off >>= 1) sum += __shfl_down(sum, off, 64);
    if (lane == 0) {
        // agent-scope store: visible to the (possibly other-XCD) last block
        __hip_atomic_store(&s[row], sum * (1.0f / (float)HW_),
                           __ATOMIC_RELAXED, __HIP_MEMORY_SCOPE_AGENT);
    }

    __shared__ float s_sh[C_];
    __shared__ float h_sh[S_];
    __shared__ int is_last;
    __syncthreads();
    if (t == 0) {
        unsigned old = __hip_atomic_fetch_add(&cnt[n], 1u, __ATOMIC_ACQ_REL,
                                              __HIP_MEMORY_SCOPE_AGENT);
        is_last = (old == 63u);
    }
    __syncthreads();
    if (!is_last) return;

    // ---- MLP for image n (exactly one block per image reaches here) ----
    s_sh[t] = __hip_atomic_load(&s[n * C_ + t], __ATOMIC_RELAXED,
                                __HIP_MEMORY_SCOPE_AGENT);
    __syncthreads();
    const int j  = t >> 4;     // hidden unit 0..15
    const int sl = t & 15;     // sub-lane 0..15
    float p = 0.f;
    #pragma unroll
    for (int k = sl; k < C_; k += 16) p += s_sh[k] * w1[j * C_ + k];
    #pragma unroll
    for (int m = 8; m; m >>= 1) p += __shfl_xor(p, m, 64);
    if (sl == 0) {
        float hv = p + b1[j];
        h_sh[j] = hv * sigmoidf_(hv);    // swish
    }
    __syncthreads();
    float a2 = b2[t];
    #pragma unroll
    for (int k = 0; k < S_; ++k) a2 += h_sh[k] * w2[t * S_ + k];
    g[n * C_ + t] = sigmoidf_(a2);
}

// Kernel 2: out[row,:] = x[row,:] * g[row]. One block per (n,c) row (known-good
// round-3 structure). x-read hits L3 (populated by pool); nt-stores keep the
// write stream from evicting x.
__global__ __launch_bounds__(256) void se_scale(const float* __restrict__ x,
                                                const float* __restrict__ g,
                                                float* __restrict__ out) {
    const int row = blockIdx.x;
    const float gv = g[row];
    const f32x4* xr = reinterpret_cast<const f32x4*>(x + (size_t)row * HW_);
    f32x4* orow = reinterpret_cast<f32x4*>(out + (size_t)row * HW_);
    for (int i = threadIdx.x; i < HW4_; i += 256) {
        f32x4 v = xr[i];
        v *= gv;
        __builtin_nontemporal_store(v, &orow[i]);
    }
}

extern "C" void kernel_launch(void* const* d_in, const int* in_sizes, int n_in,
                              void* d_out, int out_size, void* d_ws, size_t ws_size,
                              hipStream_t stream) {
    const float* x  = (const float*)d_in[0];
    const float* w1 = (const float*)d_in[1];
    const float* b1 = (const float*)d_in[2];
    const float* w2 = (const float*)d_in[3];
    const float* b2 = (const float*)d_in[4];
    float* out = (float*)d_out;

    float*    s   = (float*)d_ws;              // ROWS_ floats
    float*    g   = s + ROWS_;                 // ROWS_ floats
    unsigned* cnt = (unsigned*)(g + ROWS_);    // N_ uints

    hipMemsetAsync(cnt, 0, N_ * sizeof(unsigned), stream);
    se_pool_mlp<<<PBLOCKS_, 256, 0, stream>>>(x, w1, b1, w2, b2, s, g, cnt);
    se_scale<<<ROWS_, 256, 0, stream>>>(x, g, out);
}

// Round 6
// 103.300 us; speedup vs baseline: 2.6479x; 2.2308x over previous
//
#include <hip/hip_runtime.h>
#include <math.h>

#define N_   64
#define C_   256
#define S_   16
#define HW_  3136      // 56*56
#define HW4_ 784       // HW/4
#define ROWS_ (N_ * C_)        // 16384 (n,c) rows

typedef float f32x4 __attribute__((ext_vector_type(4)));

__device__ __forceinline__ float sigmoidf_(float v) {
    return 1.0f / (1.0f + expf(-v));
}

// Kernel 1: global average pool. One block of 256 threads per (n,c) row
// (known-good round-3 structure). Populates L3 with x for kernel 2.
__global__ __launch_bounds__(256) void se_pool(const float* __restrict__ x,
                                               float* __restrict__ s) {
    const int row = blockIdx.x;                  // n*C + c
    const f32x4* xr = reinterpret_cast<const f32x4*>(x + (size_t)row * HW_);
    float sum = 0.f;
    for (int i = threadIdx.x; i < HW4_; i += 256) {
        f32x4 v = xr[i];
        sum += (v.x + v.y) + (v.z + v.w);
    }
    #pragma unroll
    for (int off = 32; off; off >>= 1) sum += __shfl_down(sum, off, 64);
    __shared__ float partial[4];
    const int wave = threadIdx.x >> 6;
    const int lane = threadIdx.x & 63;
    if (lane == 0) partial[wave] = sum;
    __syncthreads();
    if (threadIdx.x == 0) {
        float t = (partial[0] + partial[1]) + (partial[2] + partial[3]);
        s[row] = t * (1.0f / (float)HW_);
    }
}

// Kernel 2: fused MLP + scale. One block per (n,c) row. Each block
// redundantly computes h[16] for its image (s row is 1 KB from L2, w1 is
// 16 KB L2-resident), derives the single gate g[n,c] it needs, then scales
// its row. x-read hits Infinity Cache (populated by se_pool); nt-stores keep
// the out stream from evicting x.
__global__ __launch_bounds__(256) void se_mlp_scale(
    const float* __restrict__ x,
    const float* __restrict__ s,
    const float* __restrict__ w1, const float* __restrict__ b1,
    const float* __restrict__ w2, const float* __restrict__ b2,
    float* __restrict__ out)
{
    const int row = blockIdx.x;                  // n*C + c
    const int n   = row >> 8;                    // /C_
    const int c   = row & (C_ - 1);
    const int t   = threadIdx.x;

    __shared__ float s_sh[C_];
    __shared__ float h_sh[S_];
    s_sh[t] = s[n * C_ + t];
    __syncthreads();

    // h[j] = swish(w1[j,:]·s + b1[j]); 16 outputs, one per 16-thread group.
    const int j  = t >> 4;
    const int sl = t & 15;
    float p = 0.f;
    #pragma unroll
    for (int k = sl; k < C_; k += 16) p += s_sh[k] * w1[j * C_ + k];
    #pragma unroll
    for (int m = 8; m; m >>= 1) p += __shfl_xor(p, m, 64);
    if (sl == 0) {
        float hv = p + b1[j];
        h_sh[j] = hv * sigmoidf_(hv);            // swish
    }
    __syncthreads();

    // Single gate needed by this block (uniform across threads: scalar loads).
    float a2 = b2[c];
    #pragma unroll
    for (int k = 0; k < S_; ++k) a2 += h_sh[k] * w2[c * S_ + k];
    const float gv = sigmoidf_(a2);

    // Scale the row.
    const f32x4* xr = reinterpret_cast<const f32x4*>(x + (size_t)row * HW_);
    f32x4* orow = reinterpret_cast<f32x4*>(out + (size_t)row * HW_);
    for (int i = t; i < HW4_; i += 256) {
        f32x4 v = xr[i];
        v *= gv;
        __builtin_nontemporal_store(v, &orow[i]);
    }
}

extern "C" void kernel_launch(void* const* d_in, const int* in_sizes, int n_in,
                              void* d_out, int out_size, void* d_ws, size_t ws_size,
                              hipStream_t stream) {
    const float* x  = (const float*)d_in[0];
    const float* w1 = (const float*)d_in[1];
    const float* b1 = (const float*)d_in[2];
    const float* w2 = (const float*)d_in[3];
    const float* b2 = (const float*)d_in[4];
    float* out = (float*)d_out;

    float* s = (float*)d_ws;          // ROWS_ floats

    se_pool<<<ROWS_, 256, 0, stream>>>(x, s);
    se_mlp_scale<<<ROWS_, 256, 0, stream>>>(x, s, w1, b1, w2, b2, out);
}

// Round 7
// 99.910 us; speedup vs baseline: 2.7377x; 1.0339x over previous
//
#include <hip/hip_runtime.h>
#include <math.h>

#define N_   64
#define C_   256
#define S_   16
#define HW_  3136      // 56*56
#define HW4_ 784       // HW/4 f32x4 per row; 784 = 12*64 + 16
#define ROWS_ (N_ * C_)        // 16384 (n,c) rows
#define BLK_  4096             // wave-per-row: 4 rows per 256-thread block

typedef float f32x4 __attribute__((ext_vector_type(4)));

__device__ __forceinline__ float sigmoidf_(float v) {
    return 1.0f / (1.0f + expf(-v));
}

// Kernel 1: global average pool, wave-per-row. 4096 blocks x 4 waves.
// 12 fully-unrolled independent f32x4 loads per lane + predicated 16-lane
// tail; pure in-wave shuffle reduction (no LDS, no barriers).
__global__ __launch_bounds__(256) void se_pool(const float* __restrict__ x,
                                               float* __restrict__ s) {
    const int wave = threadIdx.x >> 6;
    const int lane = threadIdx.x & 63;
    const int row  = blockIdx.x * 4 + wave;      // n*C + c
    const f32x4* xr = reinterpret_cast<const f32x4*>(x + (size_t)row * HW_);

    f32x4 acc = {0.f, 0.f, 0.f, 0.f};
    #pragma unroll
    for (int u = 0; u < 12; ++u) acc += xr[lane + 64 * u];
    float sum = (acc.x + acc.y) + (acc.z + acc.w);
    if (lane < 16) {
        f32x4 v = xr[768 + lane];
        sum += (v.x + v.y) + (v.z + v.w);
    }
    #pragma unroll
    for (int off = 32; off; off >>= 1) sum += __shfl_down(sum, off, 64);
    if (lane == 0) s[row] = sum * (1.0f / (float)HW_);
}

// Kernel 2: tiny MLP per image n. One block of 256 threads per n (64 blocks).
__global__ __launch_bounds__(256) void se_mlp(const float* __restrict__ s,
                                              const float* __restrict__ w1,
                                              const float* __restrict__ b1,
                                              const float* __restrict__ w2,
                                              const float* __restrict__ b2,
                                              float* __restrict__ g) {
    const int n = blockIdx.x;
    const int t = threadIdx.x;
    __shared__ float s_sh[C_];
    __shared__ float h_sh[S_];
    s_sh[t] = s[n * C_ + t];
    __syncthreads();

    const int j  = t >> 4;           // hidden unit 0..15
    const int sl = t & 15;           // sub-lane 0..15
    float p = 0.f;
    #pragma unroll
    for (int k = sl; k < C_; k += 16) p += s_sh[k] * w1[j * C_ + k];
    #pragma unroll
    for (int m = 8; m; m >>= 1) p += __shfl_xor(p, m, 64);
    if (sl == 0) {
        float hv = p + b1[j];
        h_sh[j] = hv * sigmoidf_(hv);     // swish
    }
    __syncthreads();

    float acc = b2[t];
    #pragma unroll
    for (int k = 0; k < S_; ++k) acc += h_sh[k] * w2[t * S_ + k];
    g[n * C_ + t] = sigmoidf_(acc);
}

// Kernel 3: out[row,:] = x[row,:] * g[row], wave-per-row, fully unrolled.
// x-read hits Infinity Cache (populated by se_pool); nt-stores keep the out
// write stream from evicting x from L3.
__global__ __launch_bounds__(256) void se_scale(const float* __restrict__ x,
                                                const float* __restrict__ g,
                                                float* __restrict__ out) {
    const int wave = threadIdx.x >> 6;
    const int lane = threadIdx.x & 63;
    const int row  = blockIdx.x * 4 + wave;
    const float gv = g[row];
    const f32x4* xr = reinterpret_cast<const f32x4*>(x + (size_t)row * HW_);
    f32x4* orow = reinterpret_cast<f32x4*>(out + (size_t)row * HW_);

    #pragma unroll
    for (int u = 0; u < 12; ++u) {
        f32x4 v = xr[lane + 64 * u];
        v *= gv;
        __builtin_nontemporal_store(v, &orow[lane + 64 * u]);
    }
    if (lane < 16) {
        f32x4 v = xr[768 + lane];
        v *= gv;
        __builtin_nontemporal_store(v, &orow[768 + lane]);
    }
}

extern "C" void kernel_launch(void* const* d_in, const int* in_sizes, int n_in,
                              void* d_out, int out_size, void* d_ws, size_t ws_size,
                              hipStream_t stream) {
    const float* x  = (const float*)d_in[0];
    const float* w1 = (const float*)d_in[1];
    const float* b1 = (const float*)d_in[2];
    const float* w2 = (const float*)d_in[3];
    const float* b2 = (const float*)d_in[4];
    float* out = (float*)d_out;

    float* s = (float*)d_ws;          // ROWS_ floats
    float* g = s + ROWS_;             // ROWS_ floats

    se_pool <<<BLK_, 256, 0, stream>>>(x, s);
    se_mlp  <<<N_,   256, 0, stream>>>(s, w1, b1, w2, b2, g);
    se_scale<<<BLK_, 256, 0, stream>>>(x, g, out);
}